// Round 5
// baseline (1204.706 us; speedup 1.0000x reference)
//
#include <hip/hip_runtime.h>

#define N_NODES 100000
#define HID 64
#define N_EDGES 1600000
#define SCAN_B 1024
#define N_SCAN_BLOCKS ((N_NODES + SCAN_B - 1) / SCAN_B)   // 98

// ---- bf16 helpers (manual, RNE) ------------------------------------------
__device__ __forceinline__ unsigned short f2bf(float f) {
    unsigned u = __float_as_uint(f);
    u = (u + 0x7FFFu + ((u >> 16) & 1u)) >> 16;
    return (unsigned short)u;
}
__device__ __forceinline__ float bf2f(unsigned short h) {
    return __uint_as_float(((unsigned)h) << 16);
}
__device__ __forceinline__ float bflo(unsigned w) { return __uint_as_float(w << 16); }
__device__ __forceinline__ float bfhi(unsigned w) { return __uint_as_float(w & 0xFFFF0000u); }

// ---------------------------------------------------------------- gather->bf16
__global__ void gather_bf16_kernel(const float* __restrict__ emb,
                                   const int* __restrict__ nid,
                                   unsigned short* __restrict__ xh) {
    int i = blockIdx.x * blockDim.x + threadIdx.x;
    const int total = N_NODES * (HID / 4);
    if (i >= total) return;
    int row = i >> 4;
    int c   = i & 15;
    int s   = nid[row];
    float4 v = reinterpret_cast<const float4*>(emb)[(size_t)s * 16 + c];
    uint2 p;
    p.x = (unsigned)f2bf(v.x) | ((unsigned)f2bf(v.y) << 16);
    p.y = (unsigned)f2bf(v.z) | ((unsigned)f2bf(v.w) << 16);
    reinterpret_cast<uint2*>(xh)[(size_t)row * 16 + c] = p;
}

// ---------------------------------------------------------------- degree (int)
__global__ void deg_kernel(const int* __restrict__ dst,
                           int* __restrict__ degi) {
    int e = blockIdx.x * blockDim.x + threadIdx.x;
    if (e < N_EDGES) atomicAdd(&degi[dst[e]], 1);
}

// ---------------------------------------------------------------- scan phase A
__global__ void scan_block(const int* __restrict__ degi,
                           int* __restrict__ row_start,
                           int* __restrict__ bsums) {
    __shared__ int s[SCAN_B];
    int gid = blockIdx.x * SCAN_B + threadIdx.x;
    int v = (gid < N_NODES) ? degi[gid] : 0;
    s[threadIdx.x] = v;
    __syncthreads();
    for (int off = 1; off < SCAN_B; off <<= 1) {
        int t = (threadIdx.x >= off) ? s[threadIdx.x - off] : 0;
        __syncthreads();
        s[threadIdx.x] += t;
        __syncthreads();
    }
    if (gid < N_NODES) row_start[gid + 1] = s[threadIdx.x];
    if (threadIdx.x == SCAN_B - 1) bsums[blockIdx.x] = s[SCAN_B - 1];
}

// ---------------------------------------------------------------- scan phase B
__global__ void scan_bsums(int* __restrict__ bsums) {
    __shared__ int s[128];
    int v = (threadIdx.x < N_SCAN_BLOCKS) ? bsums[threadIdx.x] : 0;
    s[threadIdx.x] = v;
    __syncthreads();
    for (int off = 1; off < 128; off <<= 1) {
        int t = (threadIdx.x >= off) ? s[threadIdx.x - off] : 0;
        __syncthreads();
        s[threadIdx.x] += t;
        __syncthreads();
    }
    if (threadIdx.x < N_SCAN_BLOCKS) bsums[threadIdx.x] = s[threadIdx.x] - v; // exclusive
}

// ---------------------------------------------------------------- scan phase C
__global__ void scan_add(int* __restrict__ row_start,
                         const int* __restrict__ bsums) {
    int gid = blockIdx.x * SCAN_B + threadIdx.x;
    if (gid < N_NODES) row_start[gid + 1] += bsums[blockIdx.x];
    if (gid == 0) row_start[0] = 0;
}

// ---------------------------------------------------------------- CSR fill
__global__ void fill_adj(const int* __restrict__ src,
                         const int* __restrict__ dst,
                         const int* __restrict__ row_start,
                         int* __restrict__ cursor,
                         int* __restrict__ adj) {
    int e = blockIdx.x * blockDim.x + threadIdx.x;
    if (e >= N_EDGES) return;
    int d = dst[e];
    int pos = atomicAdd(&cursor[d], 1);
    adj[row_start[d] + pos] = src[e];
}

// ---------------------------------------------------------------- fused SAGE layer
// block=512 (8 waves) x 4 blocks/CU (LDS 33KB) = 32 waves/CU, with bf16 rows so
// worst-case all-miss traffic is capped at ~250MB (R3 thrash risk halved).
// Unroll-8 gather: 8 rows x 128B = 1KB outstanding per wave.
__global__ void __launch_bounds__(512, 8)
sage_layer(const int* __restrict__ row_start,
           const int* __restrict__ adj,
           const float* __restrict__ selfmat,     // fp32 matrix for self term
           const int* __restrict__ self_idx,      // nid for layer1, null = identity
           const unsigned short* __restrict__ xh, // bf16 gather source
           const float* __restrict__ Wl,
           const float* __restrict__ Wr,
           const float* __restrict__ b,
           float* __restrict__ out_f32,           // nullable
           unsigned short* __restrict__ out_bf16,
           int relu) {
    __shared__ float sWl[HID * HID];
    __shared__ float sWr[HID * HID];
    __shared__ float sb[HID];
    for (int idx = threadIdx.x; idx < HID * HID; idx += blockDim.x) {
        int k = idx >> 6, o = idx & 63;
        sWl[idx] = Wl[o * HID + k];   // transposed: lane o reads k*64+o, 2-way (free)
        sWr[idx] = Wr[o * HID + k];
    }
    if (threadIdx.x < HID) sb[threadIdx.x] = b[threadIdx.x];
    __syncthreads();

    int lane = threadIdx.x & 63;
    int wpb = blockDim.x >> 6;
    int wid = blockIdx.x * wpb + (threadIdx.x >> 6);
    int stride = gridDim.x * wpb;
    for (int row = wid; row < N_NODES; row += stride) {
        int beg = row_start[row], end = row_start[row + 1];
        float acc = 0.0f;
        int j = beg;
        for (; j + 7 < end; j += 8) {          // 8 gathers in flight
            int s0 = adj[j],     s1 = adj[j + 1], s2 = adj[j + 2], s3 = adj[j + 3];
            int s4 = adj[j + 4], s5 = adj[j + 5], s6 = adj[j + 6], s7 = adj[j + 7];
            unsigned short v0 = xh[(size_t)s0 * HID + lane];
            unsigned short v1 = xh[(size_t)s1 * HID + lane];
            unsigned short v2 = xh[(size_t)s2 * HID + lane];
            unsigned short v3 = xh[(size_t)s3 * HID + lane];
            unsigned short v4 = xh[(size_t)s4 * HID + lane];
            unsigned short v5 = xh[(size_t)s5 * HID + lane];
            unsigned short v6 = xh[(size_t)s6 * HID + lane];
            unsigned short v7 = xh[(size_t)s7 * HID + lane];
            acc += bf2f(v0); acc += bf2f(v1); acc += bf2f(v2); acc += bf2f(v3);
            acc += bf2f(v4); acc += bf2f(v5); acc += bf2f(v6); acc += bf2f(v7);
        }
        for (; j + 3 < end; j += 4) {
            int s0 = adj[j], s1 = adj[j + 1], s2 = adj[j + 2], s3 = adj[j + 3];
            unsigned short v0 = xh[(size_t)s0 * HID + lane];
            unsigned short v1 = xh[(size_t)s1 * HID + lane];
            unsigned short v2 = xh[(size_t)s2 * HID + lane];
            unsigned short v3 = xh[(size_t)s3 * HID + lane];
            acc += bf2f(v0); acc += bf2f(v1); acc += bf2f(v2); acc += bf2f(v3);
        }
        for (; j < end; ++j) acc += bf2f(xh[(size_t)adj[j] * HID + lane]);

        int srow = self_idx ? self_idx[row] : row;
        float xv = selfmat[(size_t)srow * HID + lane];
        float d  = (float)(end - beg);
        float a  = acc / fmaxf(d, 1.0f);
        float o  = sb[lane];
        #pragma unroll
        for (int k = 0; k < HID; ++k) {
            o += __shfl(a, k)  * sWl[k * HID + lane];
            o += __shfl(xv, k) * sWr[k * HID + lane];
        }
        if (relu) o = fmaxf(o, 0.0f);
        if (out_f32) out_f32[(size_t)row * HID + lane] = o;
        out_bf16[(size_t)row * HID + lane] = f2bf(o);
    }
}

// ---------------------------------------------------------------- edge dot (bf16)
__global__ void edge_dot_kernel(const int* __restrict__ src,
                                const int* __restrict__ dst,
                                const unsigned short* __restrict__ h,
                                float* __restrict__ out) {
    int t = blockIdx.x * blockDim.x + threadIdx.x;
    int e = t >> 4;
    int c = t & 15;
    if (e >= N_EDGES) return;
    int a = src[e], bn = dst[e];
    uint2 va = reinterpret_cast<const uint2*>(h)[(size_t)a  * 16 + c];
    uint2 vb = reinterpret_cast<const uint2*>(h)[(size_t)bn * 16 + c];
    float p = bflo(va.x) * bflo(vb.x) + bfhi(va.x) * bfhi(vb.x)
            + bflo(va.y) * bflo(vb.y) + bfhi(va.y) * bfhi(vb.y);
    p += __shfl_xor(p, 1);
    p += __shfl_xor(p, 2);
    p += __shfl_xor(p, 4);
    p += __shfl_xor(p, 8);
    if (c == 0) out[e] = p;
}

extern "C" void kernel_launch(void* const* d_in, const int* in_sizes, int n_in,
                              void* d_out, int out_size, void* d_ws, size_t ws_size,
                              hipStream_t stream) {
    const float* emb = (const float*)d_in[0];
    const float* Wl1 = (const float*)d_in[1];
    const float* Wr1 = (const float*)d_in[2];
    const float* b1  = (const float*)d_in[3];
    const float* Wl2 = (const float*)d_in[4];
    const float* Wr2 = (const float*)d_in[5];
    const float* b2  = (const float*)d_in[6];
    const int*   nid = (const int*)d_in[7];
    const int*   ei  = (const int*)d_in[8];
    const int* esrc = ei;
    const int* edst = ei + N_EDGES;
    float* out = (float*)d_out;

    const size_t NH = (size_t)N_NODES * HID;   // 6.4M elements
    float* ws = (float*)d_ws;
    float* h1 = ws;                                       // [N,64] fp32
    unsigned short* xh  = (unsigned short*)(ws + NH);     // [N,64] bf16
    unsigned short* h1h = xh + NH;                        // [N,64] bf16
    unsigned short* h2h = h1h + NH;                       // [N,64] bf16
    int* ib        = (int*)(h2h + NH);
    int* degi      = ib;                          // [N]
    int* cursor    = ib + N_NODES;                // [N]
    int* row_start = ib + 2 * N_NODES;            // [N+1]
    int* adj       = ib + 3 * N_NODES + 64;       // [E]
    int* bsums     = adj + N_EDGES + 64;          // [128]

    hipMemsetAsync(degi, 0, 2 * (size_t)N_NODES * sizeof(int), stream);

    // xh = bf16(emb[node_id])
    gather_bf16_kernel<<<(N_NODES * 16 + 255) / 256, 256, 0, stream>>>(emb, nid, xh);

    // ---- CSR build (shared by both layers)
    deg_kernel<<<(N_EDGES + 255) / 256, 256, 0, stream>>>(edst, degi);
    scan_block<<<N_SCAN_BLOCKS, SCAN_B, 0, stream>>>(degi, row_start, bsums);
    scan_bsums<<<1, 128, 0, stream>>>(bsums);
    scan_add<<<N_SCAN_BLOCKS, SCAN_B, 0, stream>>>(row_start, bsums);
    fill_adj<<<(N_EDGES + 255) / 256, 256, 0, stream>>>(esrc, edst, row_start, cursor, adj);

    // ---- layer 1: self term exact from emb via nid; gathers bf16
    sage_layer<<<1024, 512, 0, stream>>>(row_start, adj, emb, nid, xh,
                                         Wl1, Wr1, b1, h1, h1h, 1);
    // ---- layer 2: self term fp32 from h1; gathers bf16; only bf16 output needed
    sage_layer<<<1024, 512, 0, stream>>>(row_start, adj, h1, nullptr, h1h,
                                         Wl2, Wr2, b2, nullptr, h2h, 0);

    // ---- edge classifier on bf16 features
    edge_dot_kernel<<<((size_t)N_EDGES * 16 + 255) / 256, 256, 0, stream>>>(esrc, edst, h2h, out);
}

// Round 6
// 501.543 us; speedup vs baseline: 2.4020x; 2.4020x over previous
//
#include <hip/hip_runtime.h>

#define N_NODES 100000
#define HID 64
#define N_EDGES 1600000
#define SCAN_B 1024
#define N_SCAN_BLOCKS ((N_NODES + SCAN_B - 1) / SCAN_B)   // 98

typedef __attribute__((ext_vector_type(8))) short bf16x8;
typedef __attribute__((ext_vector_type(4))) float f32x4;

// ---- bf16 helpers (manual, RNE) ------------------------------------------
__device__ __forceinline__ unsigned short f2bf(float f) {
    unsigned u = __float_as_uint(f);
    u = (u + 0x7FFFu + ((u >> 16) & 1u)) >> 16;
    return (unsigned short)u;
}
__device__ __forceinline__ float bf2f(unsigned short h) {
    return __uint_as_float(((unsigned)h) << 16);
}
__device__ __forceinline__ float bflo(unsigned w) { return __uint_as_float(w << 16); }
__device__ __forceinline__ float bfhi(unsigned w) { return __uint_as_float(w & 0xFFFF0000u); }

// ---------------------------------------------------------------- gather->bf16
__global__ void gather_bf16_kernel(const float* __restrict__ emb,
                                   const int* __restrict__ nid,
                                   unsigned short* __restrict__ xh) {
    int i = blockIdx.x * blockDim.x + threadIdx.x;
    const int total = N_NODES * (HID / 4);
    if (i >= total) return;
    int row = i >> 4;
    int c   = i & 15;
    int s   = nid[row];
    float4 v = reinterpret_cast<const float4*>(emb)[(size_t)s * 16 + c];
    uint2 p;
    p.x = (unsigned)f2bf(v.x) | ((unsigned)f2bf(v.y) << 16);
    p.y = (unsigned)f2bf(v.z) | ((unsigned)f2bf(v.w) << 16);
    reinterpret_cast<uint2*>(xh)[(size_t)row * 16 + c] = p;
}

// ---------------------------------------------------------------- degree (int)
__global__ void deg_kernel(const int* __restrict__ dst,
                           int* __restrict__ degi) {
    int e = blockIdx.x * blockDim.x + threadIdx.x;
    if (e < N_EDGES) atomicAdd(&degi[dst[e]], 1);
}

// ---------------------------------------------------------------- scan phase A
__global__ void scan_block(const int* __restrict__ degi,
                           int* __restrict__ row_start,
                           int* __restrict__ bsums) {
    __shared__ int s[SCAN_B];
    int gid = blockIdx.x * SCAN_B + threadIdx.x;
    int v = (gid < N_NODES) ? degi[gid] : 0;
    s[threadIdx.x] = v;
    __syncthreads();
    for (int off = 1; off < SCAN_B; off <<= 1) {
        int t = (threadIdx.x >= off) ? s[threadIdx.x - off] : 0;
        __syncthreads();
        s[threadIdx.x] += t;
        __syncthreads();
    }
    if (gid < N_NODES) row_start[gid + 1] = s[threadIdx.x];
    if (threadIdx.x == SCAN_B - 1) bsums[blockIdx.x] = s[SCAN_B - 1];
}

// ---------------------------------------------------------------- scan phase B
__global__ void scan_bsums(int* __restrict__ bsums) {
    __shared__ int s[128];
    int v = (threadIdx.x < N_SCAN_BLOCKS) ? bsums[threadIdx.x] : 0;
    s[threadIdx.x] = v;
    __syncthreads();
    for (int off = 1; off < 128; off <<= 1) {
        int t = (threadIdx.x >= off) ? s[threadIdx.x - off] : 0;
        __syncthreads();
        s[threadIdx.x] += t;
        __syncthreads();
    }
    if (threadIdx.x < N_SCAN_BLOCKS) bsums[threadIdx.x] = s[threadIdx.x] - v; // exclusive
}

// ---------------------------------------------------------------- scan phase C
__global__ void scan_add(int* __restrict__ row_start,
                         const int* __restrict__ bsums) {
    int gid = blockIdx.x * SCAN_B + threadIdx.x;
    if (gid < N_NODES) row_start[gid + 1] += bsums[blockIdx.x];
    if (gid == 0) row_start[0] = 0;
}

// ---------------------------------------------------------------- CSR fill
__global__ void fill_adj(const int* __restrict__ src,
                         const int* __restrict__ dst,
                         const int* __restrict__ row_start,
                         int* __restrict__ cursor,
                         int* __restrict__ adj) {
    int e = blockIdx.x * blockDim.x + threadIdx.x;
    if (e >= N_EDGES) return;
    int d = dst[e];
    int pos = atomicAdd(&cursor[d], 1);
    adj[row_start[d] + pos] = src[e];
}

// ---------------------------------------------------------------- aggregation
// Pure gather+mean, NO LDS (frees the DS pipe). Paired-lane: lanes 0-31 take
// even edge slots, 32-63 odd; each lane loads a dword (2 bf16 features) so a
// single load instruction has 2 rows in flight. Unroll 4 = 8 edges/wave/iter.
__global__ void agg_kernel(const int* __restrict__ row_start,
                           const int* __restrict__ adj,
                           const unsigned short* __restrict__ xh,
                           unsigned short* __restrict__ M) {
    int lane = threadIdx.x & 63;
    int half = lane >> 5;
    int c2   = lane & 31;               // dword column (features 2*c2, 2*c2+1)
    int wpb = blockDim.x >> 6;
    int wid = blockIdx.x * wpb + (threadIdx.x >> 6);
    int stride = gridDim.x * wpb;
    const unsigned* xw = (const unsigned*)xh;   // row stride = 32 dwords
    unsigned* Mw = (unsigned*)M;
    for (int row = wid; row < N_NODES; row += stride) {
        int beg = row_start[row], end = row_start[row + 1];
        float ax = 0.f, ay = 0.f;
        int j = beg + half;
        for (; j + 6 < end; j += 8) {   // 4 dword gathers in flight per half
            int s0 = adj[j], s1 = adj[j + 2], s2 = adj[j + 4], s3 = adj[j + 6];
            unsigned v0 = xw[(size_t)s0 * 32 + c2];
            unsigned v1 = xw[(size_t)s1 * 32 + c2];
            unsigned v2 = xw[(size_t)s2 * 32 + c2];
            unsigned v3 = xw[(size_t)s3 * 32 + c2];
            ax += bflo(v0) + bflo(v1) + bflo(v2) + bflo(v3);
            ay += bfhi(v0) + bfhi(v1) + bfhi(v2) + bfhi(v3);
        }
        for (; j < end; j += 2) {
            unsigned v = xw[(size_t)adj[j] * 32 + c2];
            ax += bflo(v); ay += bfhi(v);
        }
        ax += __shfl_xor(ax, 32);
        ay += __shfl_xor(ay, 32);
        if (half == 0) {
            float inv = 1.0f / fmaxf((float)(end - beg), 1.0f);
            unsigned p = (unsigned)f2bf(ax * inv) | ((unsigned)f2bf(ay * inv) << 16);
            Mw[(size_t)row * 32 + c2] = p;
        }
    }
}

// ---------------------------------------------------------------- MFMA GEMM
// H[N,64] = Am @ Wl^T + As @ Wr^T + bias  (bf16 in, fp32 acc, bf16 out)
// 16x16x32 bf16 MFMA. A-frag: A[m=lane&15][k=quad*8+j] straight from row-major
// bf16. B-frag: B[k=quad*8+j][n=lane&15] = W[ct*16+n][k] (W row-major, @W^T).
// C/D: col=lane&15, row=quad*4+reg (verified layout). Weights live in regs.
__global__ void gemm_kernel(const unsigned short* __restrict__ Am,
                            const unsigned short* __restrict__ As,
                            const float* __restrict__ Wl,
                            const float* __restrict__ Wr,
                            const float* __restrict__ bias,
                            unsigned short* __restrict__ H,
                            int relu) {
    int lane = threadIdx.x & 63;
    int m = lane & 15, quad = lane >> 4;

    bf16x8 wf[2][2][4];   // [matrix][kstep][ctile]
    for (int mat = 0; mat < 2; ++mat) {
        const float* W = mat ? Wr : Wl;
        for (int ks = 0; ks < 2; ++ks)
            for (int ct = 0; ct < 4; ++ct) {
                const float* p = W + (ct * 16 + m) * HID + ks * 32 + quad * 8;
                bf16x8 f;
                #pragma unroll
                for (int j = 0; j < 8; ++j) f[j] = (short)f2bf(p[j]);
                wf[mat][ks][ct] = f;
            }
    }
    float bv[4];
    #pragma unroll
    for (int ct = 0; ct < 4; ++ct) bv[ct] = bias[ct * 16 + m];

    int wpb = blockDim.x >> 6;
    int wid = blockIdx.x * wpb + (threadIdx.x >> 6);
    int stride = gridDim.x * wpb;
    const int NT = N_NODES / 16;   // 6250 tiles of 16 rows
    for (int t = wid; t < NT; t += stride) {
        f32x4 acc[4] = {{0,0,0,0},{0,0,0,0},{0,0,0,0},{0,0,0,0}};
        size_t rowbase = ((size_t)t * 16 + m) * HID;
        #pragma unroll
        for (int ks = 0; ks < 2; ++ks) {
            bf16x8 a0 = *(const bf16x8*)(Am + rowbase + ks * 32 + quad * 8);
            bf16x8 a1 = *(const bf16x8*)(As + rowbase + ks * 32 + quad * 8);
            #pragma unroll
            for (int ct = 0; ct < 4; ++ct) {
                acc[ct] = __builtin_amdgcn_mfma_f32_16x16x32_bf16(a0, wf[0][ks][ct], acc[ct], 0, 0, 0);
                acc[ct] = __builtin_amdgcn_mfma_f32_16x16x32_bf16(a1, wf[1][ks][ct], acc[ct], 0, 0, 0);
            }
        }
        #pragma unroll
        for (int ct = 0; ct < 4; ++ct) {
            #pragma unroll
            for (int r = 0; r < 4; ++r) {
                float v = acc[ct][r] + bv[ct];
                if (relu) v = fmaxf(v, 0.f);
                H[((size_t)t * 16 + quad * 4 + r) * HID + ct * 16 + m] = f2bf(v);
            }
        }
    }
}

// ---------------------------------------------------------------- edge dot (bf16)
__global__ void edge_dot_kernel(const int* __restrict__ src,
                                const int* __restrict__ dst,
                                const unsigned short* __restrict__ h,
                                float* __restrict__ out) {
    int t = blockIdx.x * blockDim.x + threadIdx.x;
    int e = t >> 4;
    int c = t & 15;
    if (e >= N_EDGES) return;
    int a = src[e], bn = dst[e];
    uint2 va = reinterpret_cast<const uint2*>(h)[(size_t)a  * 16 + c];
    uint2 vb = reinterpret_cast<const uint2*>(h)[(size_t)bn * 16 + c];
    float p = bflo(va.x) * bflo(vb.x) + bfhi(va.x) * bfhi(vb.x)
            + bflo(va.y) * bflo(vb.y) + bfhi(va.y) * bfhi(vb.y);
    p += __shfl_xor(p, 1);
    p += __shfl_xor(p, 2);
    p += __shfl_xor(p, 4);
    p += __shfl_xor(p, 8);
    if (c == 0) out[e] = p;
}

extern "C" void kernel_launch(void* const* d_in, const int* in_sizes, int n_in,
                              void* d_out, int out_size, void* d_ws, size_t ws_size,
                              hipStream_t stream) {
    const float* emb = (const float*)d_in[0];
    const float* Wl1 = (const float*)d_in[1];
    const float* Wr1 = (const float*)d_in[2];
    const float* b1  = (const float*)d_in[3];
    const float* Wl2 = (const float*)d_in[4];
    const float* Wr2 = (const float*)d_in[5];
    const float* b2  = (const float*)d_in[6];
    const int*   nid = (const int*)d_in[7];
    const int*   ei  = (const int*)d_in[8];
    const int* esrc = ei;
    const int* edst = ei + N_EDGES;
    float* out = (float*)d_out;

    const size_t NH = (size_t)N_NODES * HID;   // 6.4M elements
    unsigned short* xh  = (unsigned short*)d_ws;          // [N,64] bf16
    unsigned short* h1h = xh + NH;                        // [N,64] bf16
    unsigned short* h2h = h1h + NH;                       // [N,64] bf16
    unsigned short* M   = h2h + NH;                       // [N,64] bf16 (mean agg)
    int* ib        = (int*)(M + NH);
    int* degi      = ib;                          // [N]
    int* cursor    = ib + N_NODES;                // [N]
    int* row_start = ib + 2 * N_NODES;            // [N+1]
    int* adj       = ib + 3 * N_NODES + 64;       // [E]
    int* bsums     = adj + N_EDGES + 64;          // [128]

    hipMemsetAsync(degi, 0, 2 * (size_t)N_NODES * sizeof(int), stream);

    // xh = bf16(emb[node_id])
    gather_bf16_kernel<<<(N_NODES * 16 + 255) / 256, 256, 0, stream>>>(emb, nid, xh);

    // ---- CSR build (shared by both layers)
    deg_kernel<<<(N_EDGES + 255) / 256, 256, 0, stream>>>(edst, degi);
    scan_block<<<N_SCAN_BLOCKS, SCAN_B, 0, stream>>>(degi, row_start, bsums);
    scan_bsums<<<1, 128, 0, stream>>>(bsums);
    scan_add<<<N_SCAN_BLOCKS, SCAN_B, 0, stream>>>(row_start, bsums);
    fill_adj<<<(N_EDGES + 255) / 256, 256, 0, stream>>>(esrc, edst, row_start, cursor, adj);

    // ---- layer 1: aggregate then MFMA GEMM (+relu)
    agg_kernel<<<1024, 256, 0, stream>>>(row_start, adj, xh, M);
    gemm_kernel<<<512, 256, 0, stream>>>(M, xh, Wl1, Wr1, b1, h1h, 1);

    // ---- layer 2
    agg_kernel<<<1024, 256, 0, stream>>>(row_start, adj, h1h, M);
    gemm_kernel<<<512, 256, 0, stream>>>(M, h1h, Wl2, Wr2, b2, h2h, 0);

    // ---- edge classifier on bf16 features
    edge_dot_kernel<<<((size_t)N_EDGES * 16 + 255) / 256, 256, 0, stream>>>(esrc, edst, h2h, out);
}

// Round 7
// 402.312 us; speedup vs baseline: 2.9945x; 1.2467x over previous
//
#include <hip/hip_runtime.h>

#define N_NODES 100000
#define HID 64
#define N_EDGES 1600000
#define NB 391                 // ceil(N_NODES / 256) buckets of 256 nodes
#define C_EPB 6400             // edges per block in bucket_scatter (250 blocks)

typedef __attribute__((ext_vector_type(8))) short bf16x8;
typedef __attribute__((ext_vector_type(4))) float f32x4;

// ---- bf16 helpers (manual, RNE) ------------------------------------------
__device__ __forceinline__ unsigned short f2bf(float f) {
    unsigned u = __float_as_uint(f);
    u = (u + 0x7FFFu + ((u >> 16) & 1u)) >> 16;
    return (unsigned short)u;
}
__device__ __forceinline__ float bf2f(unsigned short h) {
    return __uint_as_float(((unsigned)h) << 16);
}
__device__ __forceinline__ float bflo(unsigned w) { return __uint_as_float(w << 16); }
__device__ __forceinline__ float bfhi(unsigned w) { return __uint_as_float(w & 0xFFFF0000u); }

// ---------------------------------------------------------------- gather->bf16
__global__ void gather_bf16_kernel(const float* __restrict__ emb,
                                   const int* __restrict__ nid,
                                   unsigned short* __restrict__ xh) {
    int i = blockIdx.x * blockDim.x + threadIdx.x;
    const int total = N_NODES * (HID / 4);
    if (i >= total) return;
    int row = i >> 4;
    int c   = i & 15;
    int s   = nid[row];
    float4 v = reinterpret_cast<const float4*>(emb)[(size_t)s * 16 + c];
    uint2 p;
    p.x = (unsigned)f2bf(v.x) | ((unsigned)f2bf(v.y) << 16);
    p.y = (unsigned)f2bf(v.z) | ((unsigned)f2bf(v.w) << 16);
    reinterpret_cast<uint2*>(xh)[(size_t)row * 16 + c] = p;
}

// ---------------------------------------------------------------- CSR build, pass A
// Global bucket histogram via LDS staging (bucket = dst >> 8).
__global__ void bucket_hist(const int* __restrict__ dst,
                            int* __restrict__ bhist) {
    __shared__ int h[NB];
    for (int i = threadIdx.x; i < NB; i += blockDim.x) h[i] = 0;
    __syncthreads();
    int nt = gridDim.x * blockDim.x;
    for (int e = blockIdx.x * blockDim.x + threadIdx.x; e < N_EDGES; e += nt)
        atomicAdd(&h[dst[e] >> 8], 1);
    __syncthreads();
    for (int i = threadIdx.x; i < NB; i += blockDim.x)
        if (h[i]) atomicAdd(&bhist[i], h[i]);
}

// ---------------------------------------------------------------- CSR build, pass B
// Single block: exclusive scan of 391 bucket counts -> boff, bcursor.
__global__ void bucket_scan(const int* __restrict__ bhist,
                            int* __restrict__ boff,
                            int* __restrict__ bcursor) {
    __shared__ int s[512];
    int v = (threadIdx.x < NB) ? bhist[threadIdx.x] : 0;
    s[threadIdx.x] = v;
    __syncthreads();
    for (int off = 1; off < 512; off <<= 1) {
        int t = (threadIdx.x >= off) ? s[threadIdx.x - off] : 0;
        __syncthreads();
        s[threadIdx.x] += t;
        __syncthreads();
    }
    if (threadIdx.x < NB) {
        int ex = s[threadIdx.x] - v;
        boff[threadIdx.x] = ex;
        bcursor[threadIdx.x] = ex;
    }
}

// ---------------------------------------------------------------- CSR build, pass C
// Block owns C_EPB contiguous edges: LDS-histogram them, reserve per-bucket
// ranges with ONE global atomic per (block,bucket), then write (src,dst) pairs
// in ~16-pair runs. Kills the 4B-scatter write-allocate ping-pong.
__global__ void bucket_scatter(const int* __restrict__ src,
                               const int* __restrict__ dst,
                               int* __restrict__ bcursor,
                               int2* __restrict__ pairs) {
    __shared__ int h[NB];
    __shared__ int base[NB];
    for (int i = threadIdx.x; i < NB; i += blockDim.x) h[i] = 0;
    __syncthreads();
    int e0 = blockIdx.x * C_EPB;
    int e1 = e0 + C_EPB; if (e1 > N_EDGES) e1 = N_EDGES;
    for (int e = e0 + threadIdx.x; e < e1; e += blockDim.x)
        atomicAdd(&h[dst[e] >> 8], 1);
    __syncthreads();
    for (int i = threadIdx.x; i < NB; i += blockDim.x) {
        int c = h[i];
        base[i] = c ? atomicAdd(&bcursor[i], c) : 0;
    }
    __syncthreads();
    for (int i = threadIdx.x; i < NB; i += blockDim.x) h[i] = 0;
    __syncthreads();
    for (int e = e0 + threadIdx.x; e < e1; e += blockDim.x) {
        int d = dst[e];
        int b = d >> 8;
        int slot = base[b] + atomicAdd(&h[b], 1);
        pairs[slot] = make_int2(src[e], d);
    }
}

// ---------------------------------------------------------------- CSR build, pass D
// One block per bucket (256 nodes): local count + scan in LDS, then write the
// bucket's adj slice and row_start slice contiguously (single-XCD ownership).
__global__ void bucket_csr(const int2* __restrict__ pairs,
                           const int* __restrict__ boff,
                           const int* __restrict__ bcursor,
                           int* __restrict__ row_start,
                           int* __restrict__ adj) {
    __shared__ int cnt[256];
    __shared__ int sc[256];
    int b = blockIdx.x;
    int node0 = b << 8;
    int p0 = boff[b];
    int p1 = bcursor[b];           // after pass C, bcursor[b] = end of bucket b
    int t = threadIdx.x;
    cnt[t] = 0;
    __syncthreads();
    for (int p = p0 + t; p < p1; p += 256)
        atomicAdd(&cnt[pairs[p].y & 255], 1);
    __syncthreads();
    int v = cnt[t];
    sc[t] = v;
    __syncthreads();
    for (int off = 1; off < 256; off <<= 1) {
        int u = (t >= off) ? sc[t - off] : 0;
        __syncthreads();
        sc[t] += u;
        __syncthreads();
    }
    sc[t] = p0 + sc[t] - v;        // exclusive scan + bucket base = row_start
    __syncthreads();
    int node = node0 + t;
    if (node <= N_NODES) row_start[node] = sc[t];
    __syncthreads();               // row_start read before atomics mutate sc
    for (int p = p0 + t; p < p1; p += 256) {
        int2 pr = pairs[p];
        int slot = atomicAdd(&sc[pr.y & 255], 1);
        adj[slot] = pr.x;
    }
}

// ---------------------------------------------------------------- aggregation
// Pure gather+mean, NO LDS. Paired-lane dword gathers (2 bf16/lane).
__global__ void agg_kernel(const int* __restrict__ row_start,
                           const int* __restrict__ adj,
                           const unsigned short* __restrict__ xh,
                           unsigned short* __restrict__ M) {
    int lane = threadIdx.x & 63;
    int half = lane >> 5;
    int c2   = lane & 31;
    int wpb = blockDim.x >> 6;
    int wid = blockIdx.x * wpb + (threadIdx.x >> 6);
    int stride = gridDim.x * wpb;
    const unsigned* xw = (const unsigned*)xh;
    unsigned* Mw = (unsigned*)M;
    for (int row = wid; row < N_NODES; row += stride) {
        int beg = row_start[row], end = row_start[row + 1];
        float ax = 0.f, ay = 0.f;
        int j = beg + half;
        for (; j + 6 < end; j += 8) {
            int s0 = adj[j], s1 = adj[j + 2], s2 = adj[j + 4], s3 = adj[j + 6];
            unsigned v0 = xw[(size_t)s0 * 32 + c2];
            unsigned v1 = xw[(size_t)s1 * 32 + c2];
            unsigned v2 = xw[(size_t)s2 * 32 + c2];
            unsigned v3 = xw[(size_t)s3 * 32 + c2];
            ax += bflo(v0) + bflo(v1) + bflo(v2) + bflo(v3);
            ay += bfhi(v0) + bfhi(v1) + bfhi(v2) + bfhi(v3);
        }
        for (; j < end; j += 2) {
            unsigned v = xw[(size_t)adj[j] * 32 + c2];
            ax += bflo(v); ay += bfhi(v);
        }
        ax += __shfl_xor(ax, 32);
        ay += __shfl_xor(ay, 32);
        if (half == 0) {
            float inv = 1.0f / fmaxf((float)(end - beg), 1.0f);
            unsigned p = (unsigned)f2bf(ax * inv) | ((unsigned)f2bf(ay * inv) << 16);
            Mw[(size_t)row * 32 + c2] = p;
        }
    }
}

// ---------------------------------------------------------------- MFMA GEMM
// H[N,64] = Am @ Wl^T + As @ Wr^T + bias (bf16 in, fp32 acc, bf16 out).
__global__ void gemm_kernel(const unsigned short* __restrict__ Am,
                            const unsigned short* __restrict__ As,
                            const float* __restrict__ Wl,
                            const float* __restrict__ Wr,
                            const float* __restrict__ bias,
                            unsigned short* __restrict__ H,
                            int relu) {
    int lane = threadIdx.x & 63;
    int m = lane & 15, quad = lane >> 4;

    bf16x8 wf[2][2][4];   // [matrix][kstep][ctile]
    for (int mat = 0; mat < 2; ++mat) {
        const float* W = mat ? Wr : Wl;
        for (int ks = 0; ks < 2; ++ks)
            for (int ct = 0; ct < 4; ++ct) {
                const float* p = W + (ct * 16 + m) * HID + ks * 32 + quad * 8;
                bf16x8 f;
                #pragma unroll
                for (int j = 0; j < 8; ++j) f[j] = (short)f2bf(p[j]);
                wf[mat][ks][ct] = f;
            }
    }
    float bv[4];
    #pragma unroll
    for (int ct = 0; ct < 4; ++ct) bv[ct] = bias[ct * 16 + m];

    int wpb = blockDim.x >> 6;
    int wid = blockIdx.x * wpb + (threadIdx.x >> 6);
    int stride = gridDim.x * wpb;
    const int NT = N_NODES / 16;
    for (int t = wid; t < NT; t += stride) {
        f32x4 acc[4] = {{0,0,0,0},{0,0,0,0},{0,0,0,0},{0,0,0,0}};
        size_t rowbase = ((size_t)t * 16 + m) * HID;
        #pragma unroll
        for (int ks = 0; ks < 2; ++ks) {
            bf16x8 a0 = *(const bf16x8*)(Am + rowbase + ks * 32 + quad * 8);
            bf16x8 a1 = *(const bf16x8*)(As + rowbase + ks * 32 + quad * 8);
            #pragma unroll
            for (int ct = 0; ct < 4; ++ct) {
                acc[ct] = __builtin_amdgcn_mfma_f32_16x16x32_bf16(a0, wf[0][ks][ct], acc[ct], 0, 0, 0);
                acc[ct] = __builtin_amdgcn_mfma_f32_16x16x32_bf16(a1, wf[1][ks][ct], acc[ct], 0, 0, 0);
            }
        }
        #pragma unroll
        for (int ct = 0; ct < 4; ++ct) {
            #pragma unroll
            for (int r = 0; r < 4; ++r) {
                float v = acc[ct][r] + bv[ct];
                if (relu) v = fmaxf(v, 0.f);
                H[((size_t)t * 16 + quad * 4 + r) * HID + ct * 16 + m] = f2bf(v);
            }
        }
    }
}

// ---------------------------------------------------------------- edge dot (bf16)
__global__ void edge_dot_kernel(const int* __restrict__ src,
                                const int* __restrict__ dst,
                                const unsigned short* __restrict__ h,
                                float* __restrict__ out) {
    int t = blockIdx.x * blockDim.x + threadIdx.x;
    int e = t >> 4;
    int c = t & 15;
    if (e >= N_EDGES) return;
    int a = src[e], bn = dst[e];
    uint2 va = reinterpret_cast<const uint2*>(h)[(size_t)a  * 16 + c];
    uint2 vb = reinterpret_cast<const uint2*>(h)[(size_t)bn * 16 + c];
    float p = bflo(va.x) * bflo(vb.x) + bfhi(va.x) * bfhi(vb.x)
            + bflo(va.y) * bflo(vb.y) + bfhi(va.y) * bfhi(vb.y);
    p += __shfl_xor(p, 1);
    p += __shfl_xor(p, 2);
    p += __shfl_xor(p, 4);
    p += __shfl_xor(p, 8);
    if (c == 0) out[e] = p;
}

extern "C" void kernel_launch(void* const* d_in, const int* in_sizes, int n_in,
                              void* d_out, int out_size, void* d_ws, size_t ws_size,
                              hipStream_t stream) {
    const float* emb = (const float*)d_in[0];
    const float* Wl1 = (const float*)d_in[1];
    const float* Wr1 = (const float*)d_in[2];
    const float* b1  = (const float*)d_in[3];
    const float* Wl2 = (const float*)d_in[4];
    const float* Wr2 = (const float*)d_in[5];
    const float* b2  = (const float*)d_in[6];
    const int*   nid = (const int*)d_in[7];
    const int*   ei  = (const int*)d_in[8];
    const int* esrc = ei;
    const int* edst = ei + N_EDGES;
    float* out = (float*)d_out;

    const size_t NH = (size_t)N_NODES * HID;   // 6.4M elements
    unsigned short* xh  = (unsigned short*)d_ws;          // [N,64] bf16
    unsigned short* h1h = xh + NH;                        // [N,64] bf16
    unsigned short* h2h = h1h + NH;                       // [N,64] bf16
    unsigned short* M   = h2h + NH;                       // [N,64] bf16 (mean agg)
    int* ib        = (int*)(M + NH);                      // int region (8B-aligned)
    int* row_start = ib;                          // [N+1]
    int* adj       = ib + N_NODES + 64;           // [E]
    int2* pairs    = (int2*)(adj + N_EDGES + 64); // [E] (src,dst)
    int* bhist     = (int*)(pairs + N_EDGES);     // [NB]
    int* boff      = bhist + NB + 1;              // [NB]
    int* bcursor   = boff + NB + 1;               // [NB]

    // zero bucket histogram only (tiny)
    hipMemsetAsync(bhist, 0, NB * sizeof(int), stream);

    // xh = bf16(emb[node_id])
    gather_bf16_kernel<<<(N_NODES * 16 + 255) / 256, 256, 0, stream>>>(emb, nid, xh);

    // ---- CSR build via bucket counting sort (shared by both layers)
    bucket_hist<<<256, 256, 0, stream>>>(edst, bhist);
    bucket_scan<<<1, 512, 0, stream>>>(bhist, boff, bcursor);
    bucket_scatter<<<(N_EDGES + C_EPB - 1) / C_EPB, 256, 0, stream>>>(esrc, edst, bcursor, pairs);
    bucket_csr<<<NB, 256, 0, stream>>>(pairs, boff, bcursor, row_start, adj);

    // ---- layer 1: aggregate then MFMA GEMM (+relu)
    agg_kernel<<<1024, 256, 0, stream>>>(row_start, adj, xh, M);
    gemm_kernel<<<512, 256, 0, stream>>>(M, xh, Wl1, Wr1, b1, h1h, 1);

    // ---- layer 2
    agg_kernel<<<1024, 256, 0, stream>>>(row_start, adj, h1h, M);
    gemm_kernel<<<512, 256, 0, stream>>>(M, h1h, Wl2, Wr2, b2, h2h, 0);

    // ---- edge classifier on bf16 features
    edge_dot_kernel<<<((size_t)N_EDGES * 16 + 255) / 256, 256, 0, stream>>>(esrc, edst, h2h, out);
}

// Round 8
// 354.398 us; speedup vs baseline: 3.3993x; 1.1352x over previous
//
#include <hip/hip_runtime.h>

#define N_NODES 100000
#define HID 64
#define N_EDGES 1600000
#define NB 391                 // ceil(N_NODES / 256) buckets of 256 nodes
#define C_EPB 6400             // edges per block in bucket_scatter (250 blocks)

typedef __attribute__((ext_vector_type(8))) short bf16x8;
typedef __attribute__((ext_vector_type(4))) float f32x4;

// ---- bf16 helpers (manual, RNE) ------------------------------------------
__device__ __forceinline__ unsigned short f2bf(float f) {
    unsigned u = __float_as_uint(f);
    u = (u + 0x7FFFu + ((u >> 16) & 1u)) >> 16;
    return (unsigned short)u;
}
__device__ __forceinline__ float bf2f(unsigned short h) {
    return __uint_as_float(((unsigned)h) << 16);
}
__device__ __forceinline__ float bflo(unsigned w) { return __uint_as_float(w << 16); }
__device__ __forceinline__ float bfhi(unsigned w) { return __uint_as_float(w & 0xFFFF0000u); }

// ---------------------------------------------------------------- gather->bf16
__global__ void gather_bf16_kernel(const float* __restrict__ emb,
                                   const int* __restrict__ nid,
                                   unsigned short* __restrict__ xh) {
    int i = blockIdx.x * blockDim.x + threadIdx.x;
    const int total = N_NODES * (HID / 4);
    if (i >= total) return;
    int row = i >> 4;
    int c   = i & 15;
    int s   = nid[row];
    float4 v = reinterpret_cast<const float4*>(emb)[(size_t)s * 16 + c];
    uint2 p;
    p.x = (unsigned)f2bf(v.x) | ((unsigned)f2bf(v.y) << 16);
    p.y = (unsigned)f2bf(v.z) | ((unsigned)f2bf(v.w) << 16);
    reinterpret_cast<uint2*>(xh)[(size_t)row * 16 + c] = p;
}

// ---------------------------------------------------------------- CSR build, pass A
// Global bucket histogram via LDS staging (bucket = dst >> 8). int4 edge reads.
__global__ void bucket_hist(const int* __restrict__ dst,
                            int* __restrict__ bhist) {
    __shared__ int h[NB];
    for (int i = threadIdx.x; i < NB; i += blockDim.x) h[i] = 0;
    __syncthreads();
    int nt = gridDim.x * blockDim.x;
    const int4* d4 = (const int4*)dst;
    for (int q = blockIdx.x * blockDim.x + threadIdx.x; q < N_EDGES / 4; q += nt) {
        int4 v = d4[q];
        atomicAdd(&h[v.x >> 8], 1);
        atomicAdd(&h[v.y >> 8], 1);
        atomicAdd(&h[v.z >> 8], 1);
        atomicAdd(&h[v.w >> 8], 1);
    }
    __syncthreads();
    for (int i = threadIdx.x; i < NB; i += blockDim.x)
        if (h[i]) atomicAdd(&bhist[i], h[i]);
}

// ---------------------------------------------------------------- CSR build, pass B
__global__ void bucket_scan(const int* __restrict__ bhist,
                            int* __restrict__ boff,
                            int* __restrict__ bcursor) {
    __shared__ int s[512];
    int v = (threadIdx.x < NB) ? bhist[threadIdx.x] : 0;
    s[threadIdx.x] = v;
    __syncthreads();
    for (int off = 1; off < 512; off <<= 1) {
        int t = (threadIdx.x >= off) ? s[threadIdx.x - off] : 0;
        __syncthreads();
        s[threadIdx.x] += t;
        __syncthreads();
    }
    if (threadIdx.x < NB) {
        int ex = s[threadIdx.x] - v;
        boff[threadIdx.x] = ex;
        bcursor[threadIdx.x] = ex;
    }
}

// ---------------------------------------------------------------- CSR build, pass C
__global__ void bucket_scatter(const int* __restrict__ src,
                               const int* __restrict__ dst,
                               int* __restrict__ bcursor,
                               int2* __restrict__ pairs) {
    __shared__ int h[NB];
    __shared__ int base[NB];
    for (int i = threadIdx.x; i < NB; i += blockDim.x) h[i] = 0;
    __syncthreads();
    int e0 = blockIdx.x * C_EPB;
    int e1 = e0 + C_EPB; if (e1 > N_EDGES) e1 = N_EDGES;
    for (int e = e0 + threadIdx.x; e < e1; e += blockDim.x)
        atomicAdd(&h[dst[e] >> 8], 1);
    __syncthreads();
    for (int i = threadIdx.x; i < NB; i += blockDim.x) {
        int c = h[i];
        base[i] = c ? atomicAdd(&bcursor[i], c) : 0;
    }
    __syncthreads();
    for (int i = threadIdx.x; i < NB; i += blockDim.x) h[i] = 0;
    __syncthreads();
    for (int e = e0 + threadIdx.x; e < e1; e += blockDim.x) {
        int d = dst[e];
        int b = d >> 8;
        int slot = base[b] + atomicAdd(&h[b], 1);
        pairs[slot] = make_int2(src[e], d);
    }
}

// ---------------------------------------------------------------- CSR build, pass D
__global__ void bucket_csr(const int2* __restrict__ pairs,
                           const int* __restrict__ boff,
                           const int* __restrict__ bcursor,
                           int* __restrict__ row_start,
                           int* __restrict__ adj) {
    __shared__ int cnt[256];
    __shared__ int sc[256];
    int b = blockIdx.x;
    int node0 = b << 8;
    int p0 = boff[b];
    int p1 = bcursor[b];           // after pass C, bcursor[b] = end of bucket b
    int t = threadIdx.x;
    cnt[t] = 0;
    __syncthreads();
    for (int p = p0 + t; p < p1; p += 256)
        atomicAdd(&cnt[pairs[p].y & 255], 1);
    __syncthreads();
    int v = cnt[t];
    sc[t] = v;
    __syncthreads();
    for (int off = 1; off < 256; off <<= 1) {
        int u = (t >= off) ? sc[t - off] : 0;
        __syncthreads();
        sc[t] += u;
        __syncthreads();
    }
    sc[t] = p0 + sc[t] - v;        // exclusive scan + bucket base = row_start
    __syncthreads();
    int node = node0 + t;
    if (node <= N_NODES) row_start[node] = sc[t];
    __syncthreads();               // row_start read before atomics mutate sc
    for (int p = p0 + t; p < p1; p += 256) {
        int2 pr = pairs[p];
        int slot = atomicAdd(&sc[pr.y & 255], 1);
        adj[slot] = pr.x;
    }
}

// ---------------------------------------------------------------- aggregation
// Pure gather+mean, NO LDS. 4 edge-slots x 16 lanes; each lane loads uint2
// (8B = 4 bf16 features). 16 loads x 8B in flight per wave (unroll 4/slot).
// Cross-slot reduce via shfl_xor(16,32); slot 0 writes coalesced uint2 row.
__global__ void agg_kernel(const int* __restrict__ row_start,
                           const int* __restrict__ adj,
                           const unsigned short* __restrict__ xh,
                           unsigned short* __restrict__ M) {
    int lane = threadIdx.x & 63;
    int slot = lane >> 4;               // 0..3  edge slot
    int c    = lane & 15;               // uint2 column (features 4c..4c+3)
    int wpb = blockDim.x >> 6;
    int wid = blockIdx.x * wpb + (threadIdx.x >> 6);
    int stride = gridDim.x * wpb;
    const uint2* xw = (const uint2*)xh;   // row stride = 16 uint2
    uint2* Mw = (uint2*)M;
    for (int row = wid; row < N_NODES; row += stride) {
        int beg = row_start[row], end = row_start[row + 1];
        float a0 = 0.f, a1 = 0.f, a2 = 0.f, a3 = 0.f;
        int j = beg + slot;
        for (; j + 12 < end; j += 16) {   // 4 uint2 gathers in flight per slot
            int s0 = adj[j], s1 = adj[j + 4], s2 = adj[j + 8], s3 = adj[j + 12];
            uint2 v0 = xw[(size_t)s0 * 16 + c];
            uint2 v1 = xw[(size_t)s1 * 16 + c];
            uint2 v2 = xw[(size_t)s2 * 16 + c];
            uint2 v3 = xw[(size_t)s3 * 16 + c];
            a0 += bflo(v0.x) + bflo(v1.x) + bflo(v2.x) + bflo(v3.x);
            a1 += bfhi(v0.x) + bfhi(v1.x) + bfhi(v2.x) + bfhi(v3.x);
            a2 += bflo(v0.y) + bflo(v1.y) + bflo(v2.y) + bflo(v3.y);
            a3 += bfhi(v0.y) + bfhi(v1.y) + bfhi(v2.y) + bfhi(v3.y);
        }
        for (; j < end; j += 4) {
            uint2 v = xw[(size_t)adj[j] * 16 + c];
            a0 += bflo(v.x); a1 += bfhi(v.x);
            a2 += bflo(v.y); a3 += bfhi(v.y);
        }
        // reduce across the 4 slots
        a0 += __shfl_xor(a0, 16); a0 += __shfl_xor(a0, 32);
        a1 += __shfl_xor(a1, 16); a1 += __shfl_xor(a1, 32);
        a2 += __shfl_xor(a2, 16); a2 += __shfl_xor(a2, 32);
        a3 += __shfl_xor(a3, 16); a3 += __shfl_xor(a3, 32);
        if (slot == 0) {
            float inv = 1.0f / fmaxf((float)(end - beg), 1.0f);
            uint2 p;
            p.x = (unsigned)f2bf(a0 * inv) | ((unsigned)f2bf(a1 * inv) << 16);
            p.y = (unsigned)f2bf(a2 * inv) | ((unsigned)f2bf(a3 * inv) << 16);
            Mw[(size_t)row * 16 + c] = p;   // 16 lanes x 8B = 128B coalesced
        }
    }
}

// ---------------------------------------------------------------- MFMA GEMM
// H[N,64] = Am @ Wl^T + As @ Wr^T + bias (bf16 in, fp32 acc, bf16 out).
__global__ void gemm_kernel(const unsigned short* __restrict__ Am,
                            const unsigned short* __restrict__ As,
                            const float* __restrict__ Wl,
                            const float* __restrict__ Wr,
                            const float* __restrict__ bias,
                            unsigned short* __restrict__ H,
                            int relu) {
    int lane = threadIdx.x & 63;
    int m = lane & 15, quad = lane >> 4;

    bf16x8 wf[2][2][4];   // [matrix][kstep][ctile]
    for (int mat = 0; mat < 2; ++mat) {
        const float* W = mat ? Wr : Wl;
        for (int ks = 0; ks < 2; ++ks)
            for (int ct = 0; ct < 4; ++ct) {
                const float* p = W + (ct * 16 + m) * HID + ks * 32 + quad * 8;
                bf16x8 f;
                #pragma unroll
                for (int j = 0; j < 8; ++j) f[j] = (short)f2bf(p[j]);
                wf[mat][ks][ct] = f;
            }
    }
    float bv[4];
    #pragma unroll
    for (int ct = 0; ct < 4; ++ct) bv[ct] = bias[ct * 16 + m];

    int wpb = blockDim.x >> 6;
    int wid = blockIdx.x * wpb + (threadIdx.x >> 6);
    int stride = gridDim.x * wpb;
    const int NT = N_NODES / 16;
    for (int t = wid; t < NT; t += stride) {
        f32x4 acc[4] = {{0,0,0,0},{0,0,0,0},{0,0,0,0},{0,0,0,0}};
        size_t rowbase = ((size_t)t * 16 + m) * HID;
        #pragma unroll
        for (int ks = 0; ks < 2; ++ks) {
            bf16x8 a0 = *(const bf16x8*)(Am + rowbase + ks * 32 + quad * 8);
            bf16x8 a1 = *(const bf16x8*)(As + rowbase + ks * 32 + quad * 8);
            #pragma unroll
            for (int ct = 0; ct < 4; ++ct) {
                acc[ct] = __builtin_amdgcn_mfma_f32_16x16x32_bf16(a0, wf[0][ks][ct], acc[ct], 0, 0, 0);
                acc[ct] = __builtin_amdgcn_mfma_f32_16x16x32_bf16(a1, wf[1][ks][ct], acc[ct], 0, 0, 0);
            }
        }
        #pragma unroll
        for (int ct = 0; ct < 4; ++ct) {
            #pragma unroll
            for (int r = 0; r < 4; ++r) {
                float v = acc[ct][r] + bv[ct];
                if (relu) v = fmaxf(v, 0.f);
                H[((size_t)t * 16 + quad * 4 + r) * HID + ct * 16 + m] = f2bf(v);
            }
        }
    }
}

// ---------------------------------------------------------------- edge dot (bf16)
// 8 lanes/edge, uint4 (16B) loads -> 8 edges/wave, 16 row-loads in flight.
__global__ void edge_dot_kernel(const int* __restrict__ src,
                                const int* __restrict__ dst,
                                const unsigned short* __restrict__ h,
                                float* __restrict__ out) {
    int t = blockIdx.x * blockDim.x + threadIdx.x;
    int e = t >> 3;
    int c = t & 7;
    if (e >= N_EDGES) return;
    int a = src[e], bn = dst[e];
    uint4 va = reinterpret_cast<const uint4*>(h)[(size_t)a  * 8 + c];
    uint4 vb = reinterpret_cast<const uint4*>(h)[(size_t)bn * 8 + c];
    float p = bflo(va.x) * bflo(vb.x) + bfhi(va.x) * bfhi(vb.x)
            + bflo(va.y) * bflo(vb.y) + bfhi(va.y) * bfhi(vb.y)
            + bflo(va.z) * bflo(vb.z) + bfhi(va.z) * bfhi(vb.z)
            + bflo(va.w) * bflo(vb.w) + bfhi(va.w) * bfhi(vb.w);
    p += __shfl_xor(p, 1);
    p += __shfl_xor(p, 2);
    p += __shfl_xor(p, 4);
    if (c == 0) out[e] = p;
}

extern "C" void kernel_launch(void* const* d_in, const int* in_sizes, int n_in,
                              void* d_out, int out_size, void* d_ws, size_t ws_size,
                              hipStream_t stream) {
    const float* emb = (const float*)d_in[0];
    const float* Wl1 = (const float*)d_in[1];
    const float* Wr1 = (const float*)d_in[2];
    const float* b1  = (const float*)d_in[3];
    const float* Wl2 = (const float*)d_in[4];
    const float* Wr2 = (const float*)d_in[5];
    const float* b2  = (const float*)d_in[6];
    const int*   nid = (const int*)d_in[7];
    const int*   ei  = (const int*)d_in[8];
    const int* esrc = ei;
    const int* edst = ei + N_EDGES;
    float* out = (float*)d_out;

    const size_t NH = (size_t)N_NODES * HID;   // 6.4M elements
    unsigned short* xh  = (unsigned short*)d_ws;          // [N,64] bf16
    unsigned short* h1h = xh + NH;                        // [N,64] bf16
    unsigned short* h2h = h1h + NH;                       // [N,64] bf16
    unsigned short* M   = h2h + NH;                       // [N,64] bf16 (mean agg)
    int* ib        = (int*)(M + NH);                      // int region
    int* row_start = ib;                          // [N+1]
    int* adj       = ib + N_NODES + 64;           // [E]
    int2* pairs    = (int2*)(adj + N_EDGES + 64); // [E] (src,dst)
    int* bhist     = (int*)(pairs + N_EDGES);     // [NB]
    int* boff      = bhist + NB + 1;              // [NB]
    int* bcursor   = boff + NB + 1;               // [NB]

    hipMemsetAsync(bhist, 0, NB * sizeof(int), stream);

    // xh = bf16(emb[node_id])
    gather_bf16_kernel<<<(N_NODES * 16 + 255) / 256, 256, 0, stream>>>(emb, nid, xh);

    // ---- CSR build via bucket counting sort (shared by both layers)
    bucket_hist<<<256, 256, 0, stream>>>(edst, bhist);
    bucket_scan<<<1, 512, 0, stream>>>(bhist, boff, bcursor);
    bucket_scatter<<<(N_EDGES + C_EPB - 1) / C_EPB, 256, 0, stream>>>(esrc, edst, bcursor, pairs);
    bucket_csr<<<NB, 256, 0, stream>>>(pairs, boff, bcursor, row_start, adj);

    // ---- layer 1: aggregate then MFMA GEMM (+relu)
    agg_kernel<<<1024, 256, 0, stream>>>(row_start, adj, xh, M);
    gemm_kernel<<<512, 256, 0, stream>>>(M, xh, Wl1, Wr1, b1, h1h, 1);

    // ---- layer 2
    agg_kernel<<<1024, 256, 0, stream>>>(row_start, adj, h1h, M);
    gemm_kernel<<<512, 256, 0, stream>>>(M, h1h, Wl2, Wr2, b2, h2h, 0);

    // ---- edge classifier on bf16 features
    edge_dot_kernel<<<((size_t)N_EDGES * 8 + 255) / 256, 256, 0, stream>>>(esrc, edst, h2h, out);
}

// Round 9
// 304.322 us; speedup vs baseline: 3.9587x; 1.1645x over previous
//
#include <hip/hip_runtime.h>

#define N_NODES 100000
#define HID 64
#define N_EDGES 1600000
#define NB 391                 // ceil(N_NODES / 256) buckets of 256 nodes
#define C_EPB 6400             // edges per block in bucket_scatter (250 blocks)

typedef __attribute__((ext_vector_type(8))) short bf16x8;
typedef __attribute__((ext_vector_type(4))) float f32x4;

// ---- bf16 helpers (manual, RNE) ------------------------------------------
__device__ __forceinline__ unsigned short f2bf(float f) {
    unsigned u = __float_as_uint(f);
    u = (u + 0x7FFFu + ((u >> 16) & 1u)) >> 16;
    return (unsigned short)u;
}
__device__ __forceinline__ float bf2f(unsigned short h) {
    return __uint_as_float(((unsigned)h) << 16);
}
__device__ __forceinline__ float bflo(unsigned w) { return __uint_as_float(w << 16); }
__device__ __forceinline__ float bfhi(unsigned w) { return __uint_as_float(w & 0xFFFF0000u); }

// ---------------------------------------------------------------- gather->bf16
__global__ void gather_bf16_kernel(const float* __restrict__ emb,
                                   const int* __restrict__ nid,
                                   unsigned short* __restrict__ xh) {
    int i = blockIdx.x * blockDim.x + threadIdx.x;
    const int total = N_NODES * (HID / 4);
    if (i >= total) return;
    int row = i >> 4;
    int c   = i & 15;
    int s   = nid[row];
    float4 v = reinterpret_cast<const float4*>(emb)[(size_t)s * 16 + c];
    uint2 p;
    p.x = (unsigned)f2bf(v.x) | ((unsigned)f2bf(v.y) << 16);
    p.y = (unsigned)f2bf(v.z) | ((unsigned)f2bf(v.w) << 16);
    reinterpret_cast<uint2*>(xh)[(size_t)row * 16 + c] = p;
}

// ---------------------------------------------------------------- CSR build, pass A
__global__ void bucket_hist(const int* __restrict__ dst,
                            int* __restrict__ bhist) {
    __shared__ int h[NB];
    for (int i = threadIdx.x; i < NB; i += blockDim.x) h[i] = 0;
    __syncthreads();
    int nt = gridDim.x * blockDim.x;
    const int4* d4 = (const int4*)dst;
    for (int q = blockIdx.x * blockDim.x + threadIdx.x; q < N_EDGES / 4; q += nt) {
        int4 v = d4[q];
        atomicAdd(&h[v.x >> 8], 1);
        atomicAdd(&h[v.y >> 8], 1);
        atomicAdd(&h[v.z >> 8], 1);
        atomicAdd(&h[v.w >> 8], 1);
    }
    __syncthreads();
    for (int i = threadIdx.x; i < NB; i += blockDim.x)
        if (h[i]) atomicAdd(&bhist[i], h[i]);
}

// ---------------------------------------------------------------- CSR build, pass B
__global__ void bucket_scan(const int* __restrict__ bhist,
                            int* __restrict__ boff,
                            int* __restrict__ bcursor) {
    __shared__ int s[512];
    int v = (threadIdx.x < NB) ? bhist[threadIdx.x] : 0;
    s[threadIdx.x] = v;
    __syncthreads();
    for (int off = 1; off < 512; off <<= 1) {
        int t = (threadIdx.x >= off) ? s[threadIdx.x - off] : 0;
        __syncthreads();
        s[threadIdx.x] += t;
        __syncthreads();
    }
    if (threadIdx.x < NB) {
        int ex = s[threadIdx.x] - v;
        boff[threadIdx.x] = ex;
        bcursor[threadIdx.x] = ex;
    }
}

// ---------------------------------------------------------------- CSR build, pass C
__global__ void bucket_scatter(const int* __restrict__ src,
                               const int* __restrict__ dst,
                               int* __restrict__ bcursor,
                               int2* __restrict__ pairs) {
    __shared__ int h[NB];
    __shared__ int base[NB];
    for (int i = threadIdx.x; i < NB; i += blockDim.x) h[i] = 0;
    __syncthreads();
    int e0 = blockIdx.x * C_EPB;
    int e1 = e0 + C_EPB; if (e1 > N_EDGES) e1 = N_EDGES;
    for (int e = e0 + threadIdx.x; e < e1; e += blockDim.x)
        atomicAdd(&h[dst[e] >> 8], 1);
    __syncthreads();
    for (int i = threadIdx.x; i < NB; i += blockDim.x) {
        int c = h[i];
        base[i] = c ? atomicAdd(&bcursor[i], c) : 0;
    }
    __syncthreads();
    for (int i = threadIdx.x; i < NB; i += blockDim.x) h[i] = 0;
    __syncthreads();
    for (int e = e0 + threadIdx.x; e < e1; e += blockDim.x) {
        int d = dst[e];
        int b = d >> 8;
        int slot = base[b] + atomicAdd(&h[b], 1);
        pairs[slot] = make_int2(src[e], d);
    }
}

// ---------------------------------------------------------------- CSR build, pass D
__global__ void bucket_csr(const int2* __restrict__ pairs,
                           const int* __restrict__ boff,
                           const int* __restrict__ bcursor,
                           int* __restrict__ row_start,
                           int* __restrict__ adj) {
    __shared__ int cnt[256];
    __shared__ int sc[256];
    int b = blockIdx.x;
    int node0 = b << 8;
    int p0 = boff[b];
    int p1 = bcursor[b];           // after pass C, bcursor[b] = end of bucket b
    int t = threadIdx.x;
    cnt[t] = 0;
    __syncthreads();
    for (int p = p0 + t; p < p1; p += 256)
        atomicAdd(&cnt[pairs[p].y & 255], 1);
    __syncthreads();
    int v = cnt[t];
    sc[t] = v;
    __syncthreads();
    for (int off = 1; off < 256; off <<= 1) {
        int u = (t >= off) ? sc[t - off] : 0;
        __syncthreads();
        sc[t] += u;
        __syncthreads();
    }
    sc[t] = p0 + sc[t] - v;        // exclusive scan + bucket base = row_start
    __syncthreads();
    int node = node0 + t;
    if (node <= N_NODES) row_start[node] = sc[t];
    __syncthreads();               // row_start read before atomics mutate sc
    for (int p = p0 + t; p < p1; p += 256) {
        int2 pr = pairs[p];
        int slot = atomicAdd(&sc[pr.y & 255], 1);
        adj[slot] = pr.x;
    }
}

// ---------------------------------------------------------------- aggregation
// Pure gather+mean, NO LDS. 4 edge-slots x 16 lanes, uint2 loads.
// Grid 2048 (8 blocks/CU -> 32 waves/CU): agg is latency-bound at 1.2 TB/s
// fill (R8), well under the ~3.7 TB/s L2-miss path ceiling (R3/R5).
__global__ void agg_kernel(const int* __restrict__ row_start,
                           const int* __restrict__ adj,
                           const unsigned short* __restrict__ xh,
                           unsigned short* __restrict__ M) {
    int lane = threadIdx.x & 63;
    int slot = lane >> 4;               // 0..3  edge slot
    int c    = lane & 15;               // uint2 column (features 4c..4c+3)
    int wpb = blockDim.x >> 6;
    int wid = blockIdx.x * wpb + (threadIdx.x >> 6);
    int stride = gridDim.x * wpb;
    const uint2* xw = (const uint2*)xh;   // row stride = 16 uint2
    uint2* Mw = (uint2*)M;
    for (int row = wid; row < N_NODES; row += stride) {
        int beg = row_start[row], end = row_start[row + 1];
        float a0 = 0.f, a1 = 0.f, a2 = 0.f, a3 = 0.f;
        int j = beg + slot;
        for (; j + 12 < end; j += 16) {   // 4 uint2 gathers in flight per slot
            int s0 = adj[j], s1 = adj[j + 4], s2 = adj[j + 8], s3 = adj[j + 12];
            uint2 v0 = xw[(size_t)s0 * 16 + c];
            uint2 v1 = xw[(size_t)s1 * 16 + c];
            uint2 v2 = xw[(size_t)s2 * 16 + c];
            uint2 v3 = xw[(size_t)s3 * 16 + c];
            a0 += bflo(v0.x) + bflo(v1.x) + bflo(v2.x) + bflo(v3.x);
            a1 += bfhi(v0.x) + bfhi(v1.x) + bfhi(v2.x) + bfhi(v3.x);
            a2 += bflo(v0.y) + bflo(v1.y) + bflo(v2.y) + bflo(v3.y);
            a3 += bfhi(v0.y) + bfhi(v1.y) + bfhi(v2.y) + bfhi(v3.y);
        }
        for (; j < end; j += 4) {
            uint2 v = xw[(size_t)adj[j] * 16 + c];
            a0 += bflo(v.x); a1 += bfhi(v.x);
            a2 += bflo(v.y); a3 += bfhi(v.y);
        }
        a0 += __shfl_xor(a0, 16); a0 += __shfl_xor(a0, 32);
        a1 += __shfl_xor(a1, 16); a1 += __shfl_xor(a1, 32);
        a2 += __shfl_xor(a2, 16); a2 += __shfl_xor(a2, 32);
        a3 += __shfl_xor(a3, 16); a3 += __shfl_xor(a3, 32);
        if (slot == 0) {
            float inv = 1.0f / fmaxf((float)(end - beg), 1.0f);
            uint2 p;
            p.x = (unsigned)f2bf(a0 * inv) | ((unsigned)f2bf(a1 * inv) << 16);
            p.y = (unsigned)f2bf(a2 * inv) | ((unsigned)f2bf(a3 * inv) << 16);
            Mw[(size_t)row * 16 + c] = p;   // 16 lanes x 8B = 128B coalesced
        }
    }
}

// ---------------------------------------------------------------- MFMA GEMM
__global__ void gemm_kernel(const unsigned short* __restrict__ Am,
                            const unsigned short* __restrict__ As,
                            const float* __restrict__ Wl,
                            const float* __restrict__ Wr,
                            const float* __restrict__ bias,
                            unsigned short* __restrict__ H,
                            int relu) {
    int lane = threadIdx.x & 63;
    int m = lane & 15, quad = lane >> 4;

    bf16x8 wf[2][2][4];   // [matrix][kstep][ctile]
    for (int mat = 0; mat < 2; ++mat) {
        const float* W = mat ? Wr : Wl;
        for (int ks = 0; ks < 2; ++ks)
            for (int ct = 0; ct < 4; ++ct) {
                const float* p = W + (ct * 16 + m) * HID + ks * 32 + quad * 8;
                bf16x8 f;
                #pragma unroll
                for (int j = 0; j < 8; ++j) f[j] = (short)f2bf(p[j]);
                wf[mat][ks][ct] = f;
            }
    }
    float bv[4];
    #pragma unroll
    for (int ct = 0; ct < 4; ++ct) bv[ct] = bias[ct * 16 + m];

    int wpb = blockDim.x >> 6;
    int wid = blockIdx.x * wpb + (threadIdx.x >> 6);
    int stride = gridDim.x * wpb;
    const int NT = N_NODES / 16;
    for (int t = wid; t < NT; t += stride) {
        f32x4 acc[4] = {{0,0,0,0},{0,0,0,0},{0,0,0,0},{0,0,0,0}};
        size_t rowbase = ((size_t)t * 16 + m) * HID;
        #pragma unroll
        for (int ks = 0; ks < 2; ++ks) {
            bf16x8 a0 = *(const bf16x8*)(Am + rowbase + ks * 32 + quad * 8);
            bf16x8 a1 = *(const bf16x8*)(As + rowbase + ks * 32 + quad * 8);
            #pragma unroll
            for (int ct = 0; ct < 4; ++ct) {
                acc[ct] = __builtin_amdgcn_mfma_f32_16x16x32_bf16(a0, wf[0][ks][ct], acc[ct], 0, 0, 0);
                acc[ct] = __builtin_amdgcn_mfma_f32_16x16x32_bf16(a1, wf[1][ks][ct], acc[ct], 0, 0, 0);
            }
        }
        #pragma unroll
        for (int ct = 0; ct < 4; ++ct) {
            #pragma unroll
            for (int r = 0; r < 4; ++r) {
                float v = acc[ct][r] + bv[ct];
                if (relu) v = fmaxf(v, 0.f);
                H[((size_t)t * 16 + quad * 4 + r) * HID + ct * 16 + m] = f2bf(v);
            }
        }
    }
}

// ---------------------------------------------------------------- edge dot (bf16)
// 8 lanes per 2 consecutive edges: 4 uint4 loads/lane in flight (2x R8),
// coalesced float2 output write.
__global__ void edge_dot_kernel(const int* __restrict__ src,
                                const int* __restrict__ dst,
                                const unsigned short* __restrict__ h,
                                float* __restrict__ out) {
    int t = blockIdx.x * blockDim.x + threadIdx.x;
    int g = t >> 3;                 // edge-pair group
    int c = t & 7;
    int e0 = g * 2;
    if (e0 >= N_EDGES) return;
    int a0 = src[e0],     b0 = dst[e0];
    int a1 = src[e0 + 1], b1 = dst[e0 + 1];
    const uint4* h4 = reinterpret_cast<const uint4*>(h);
    uint4 va0 = h4[(size_t)a0 * 8 + c];
    uint4 vb0 = h4[(size_t)b0 * 8 + c];
    uint4 va1 = h4[(size_t)a1 * 8 + c];
    uint4 vb1 = h4[(size_t)b1 * 8 + c];
    float p0 = bflo(va0.x) * bflo(vb0.x) + bfhi(va0.x) * bfhi(vb0.x)
             + bflo(va0.y) * bflo(vb0.y) + bfhi(va0.y) * bfhi(vb0.y)
             + bflo(va0.z) * bflo(vb0.z) + bfhi(va0.z) * bfhi(vb0.z)
             + bflo(va0.w) * bflo(vb0.w) + bfhi(va0.w) * bfhi(vb0.w);
    float p1 = bflo(va1.x) * bflo(vb1.x) + bfhi(va1.x) * bfhi(vb1.x)
             + bflo(va1.y) * bflo(vb1.y) + bfhi(va1.y) * bfhi(vb1.y)
             + bflo(va1.z) * bflo(vb1.z) + bfhi(va1.z) * bfhi(vb1.z)
             + bflo(va1.w) * bflo(vb1.w) + bfhi(va1.w) * bfhi(vb1.w);
    p0 += __shfl_xor(p0, 1); p0 += __shfl_xor(p0, 2); p0 += __shfl_xor(p0, 4);
    p1 += __shfl_xor(p1, 1); p1 += __shfl_xor(p1, 2); p1 += __shfl_xor(p1, 4);
    if (c == 0) reinterpret_cast<float2*>(out)[g] = make_float2(p0, p1);
}

extern "C" void kernel_launch(void* const* d_in, const int* in_sizes, int n_in,
                              void* d_out, int out_size, void* d_ws, size_t ws_size,
                              hipStream_t stream) {
    const float* emb = (const float*)d_in[0];
    const float* Wl1 = (const float*)d_in[1];
    const float* Wr1 = (const float*)d_in[2];
    const float* b1  = (const float*)d_in[3];
    const float* Wl2 = (const float*)d_in[4];
    const float* Wr2 = (const float*)d_in[5];
    const float* b2  = (const float*)d_in[6];
    const int*   nid = (const int*)d_in[7];
    const int*   ei  = (const int*)d_in[8];
    const int* esrc = ei;
    const int* edst = ei + N_EDGES;
    float* out = (float*)d_out;

    const size_t NH = (size_t)N_NODES * HID;   // 6.4M elements
    unsigned short* xh  = (unsigned short*)d_ws;          // [N,64] bf16
    unsigned short* h1h = xh + NH;                        // [N,64] bf16
    unsigned short* h2h = h1h + NH;                       // [N,64] bf16
    unsigned short* M   = h2h + NH;                       // [N,64] bf16 (mean agg)
    int* ib        = (int*)(M + NH);                      // int region
    int* row_start = ib;                          // [N+1]
    int* adj       = ib + N_NODES + 64;           // [E]
    int2* pairs    = (int2*)(adj + N_EDGES + 64); // [E] (src,dst)
    int* bhist     = (int*)(pairs + N_EDGES);     // [NB]
    int* boff      = bhist + NB + 1;              // [NB]
    int* bcursor   = boff + NB + 1;               // [NB]

    hipMemsetAsync(bhist, 0, NB * sizeof(int), stream);

    // xh = bf16(emb[node_id])
    gather_bf16_kernel<<<(N_NODES * 16 + 255) / 256, 256, 0, stream>>>(emb, nid, xh);

    // ---- CSR build via bucket counting sort (shared by both layers)
    bucket_hist<<<256, 256, 0, stream>>>(edst, bhist);
    bucket_scan<<<1, 512, 0, stream>>>(bhist, boff, bcursor);
    bucket_scatter<<<(N_EDGES + C_EPB - 1) / C_EPB, 256, 0, stream>>>(esrc, edst, bcursor, pairs);
    bucket_csr<<<NB, 256, 0, stream>>>(pairs, boff, bcursor, row_start, adj);

    // ---- layer 1: aggregate then MFMA GEMM (+relu)
    agg_kernel<<<2048, 256, 0, stream>>>(row_start, adj, xh, M);
    gemm_kernel<<<512, 256, 0, stream>>>(M, xh, Wl1, Wr1, b1, h1h, 1);

    // ---- layer 2
    agg_kernel<<<2048, 256, 0, stream>>>(row_start, adj, h1h, M);
    gemm_kernel<<<512, 256, 0, stream>>>(M, h1h, Wl2, Wr2, b2, h2h, 0);

    // ---- edge classifier on bf16 features
    edge_dot_kernel<<<((size_t)(N_EDGES / 2) * 8 + 255) / 256, 256, 0, stream>>>(esrc, edst, h2h, out);
}